// Round 3
// baseline (4046.556 us; speedup 1.0000x reference)
//
#include <hip/hip_runtime.h>
#include <math.h>

#define B_   16
#define S_   1024
#define D_   768
#define DFF_ 3072
#define NTOK (B_ * S_)

constexpr int TM = 64, TN = 64, TK = 16;

// ---------------------------------------------------------------------------
// Tiled fp32 GEMM: C[M,N] = A[M,K] @ B(K,N or N,K if TRANS_B) + epilogue
// EPI 0: +bias (bias may be null)
// EPI 1: gelu_exact(acc + bias)
// EPI 2: acc*scale + gumbel(U)   (scores path; U has C's layout)
// Batched via blockIdx.z with element strides bsA/bsB/bsC (0 = shared).
// ---------------------------------------------------------------------------
template <int EPI, bool TRANS_B>
__global__ __launch_bounds__(256) void gemm_f32(
    const float* __restrict__ A, const float* __restrict__ Bm,
    const float* __restrict__ bias, const float* __restrict__ U,
    float* __restrict__ C, int M, int N, int K,
    long bsA, long bsB, long bsC, float scale)
{
    const int bz = blockIdx.z;
    A  += (long)bz * bsA;
    Bm += (long)bz * bsB;
    C  += (long)bz * bsC;
    if (EPI == 2) U += (long)bz * bsC;

    __shared__ __align__(16) float As[TK][TM + 4];  // pitch 68 floats = 272 B
    __shared__ __align__(16) float Bs[TK][TN + 4];

    const int tid  = threadIdx.x;
    const int brow = blockIdx.y * TM;
    const int bcol = blockIdx.x * TN;

    const int tm = (tid >> 4) << 2;  // 0..60 step 4
    const int tn = (tid & 15) << 2;  // 0..60 step 4

    float acc[4][4] = {};

    // A-tile load mapping: 64 rows x 16 k, 4 rows/thread
    const int a_k = tid & 15;  // contiguous k across lanes -> coalesced
    const int a_m = tid >> 4;  // 0..15; rows a_m + 16*i
    // B-tile load mapping (NN): 16 k x 64 n, 4 k-rows/thread
    const int b_n = tid & 63;  // contiguous n across lanes -> coalesced
    const int b_k = tid >> 6;  // 0..3; rows b_k + 4*i

    for (int k0 = 0; k0 < K; k0 += TK) {
#pragma unroll
        for (int i = 0; i < 4; ++i) {
            int m = a_m + 16 * i;
            As[a_k][m] = A[(long)(brow + m) * K + (k0 + a_k)];
        }
        if (TRANS_B) {
#pragma unroll
            for (int i = 0; i < 4; ++i) {
                int n = a_m + 16 * i;
                Bs[a_k][n] = Bm[(long)(bcol + n) * K + (k0 + a_k)];
            }
        } else {
#pragma unroll
            for (int i = 0; i < 4; ++i) {
                int kk = b_k + 4 * i;
                Bs[kk][b_n] = Bm[(long)(k0 + kk) * N + (bcol + b_n)];
            }
        }
        __syncthreads();

#pragma unroll
        for (int kk = 0; kk < TK; ++kk) {
            float4 av = *reinterpret_cast<const float4*>(&As[kk][tm]);
            float4 bv = *reinterpret_cast<const float4*>(&Bs[kk][tn]);
            float a4[4] = {av.x, av.y, av.z, av.w};
            float b4[4] = {bv.x, bv.y, bv.z, bv.w};
#pragma unroll
            for (int i = 0; i < 4; ++i)
#pragma unroll
                for (int j = 0; j < 4; ++j)
                    acc[i][j] = fmaf(a4[i], b4[j], acc[i][j]);
        }
        __syncthreads();
    }

#pragma unroll
    for (int i = 0; i < 4; ++i) {
        const int row = brow + tm + i;
#pragma unroll
        for (int j = 0; j < 4; ++j) {
            const int col = bcol + tn + j;
            float val = acc[i][j];
            if (EPI == 0) {
                if (bias) val += bias[col];
            } else if (EPI == 1) {
                val += bias[col];
                val = 0.5f * val * (1.0f + erff(val * 0.70710678118654752f));
            } else if (EPI == 2) {
                float u = U[(long)row * N + col];
                val = val * scale - logf(-logf(u));
            }
            C[(long)row * N + col] = val;
        }
    }
}

// ---------------------------------------------------------------------------
// Row softmax, in place. One 256-thread block per row of length S_=1024.
// ---------------------------------------------------------------------------
__global__ __launch_bounds__(256) void softmax_rows(float* __restrict__ scores)
{
    const long row = blockIdx.x;
    float* p = scores + row * (long)S_;
    const int tid  = threadIdx.x;
    const int lane = tid & 63, wid = tid >> 6;

    float v[4];
    float mx = -INFINITY;
#pragma unroll
    for (int i = 0; i < 4; ++i) {
        v[i] = p[tid + 256 * i];
        mx = fmaxf(mx, v[i]);
    }
#pragma unroll
    for (int o = 1; o < 64; o <<= 1) mx = fmaxf(mx, __shfl_xor(mx, o));

    __shared__ float rmax[4], rsum[4];
    if (lane == 0) rmax[wid] = mx;
    __syncthreads();
    mx = fmaxf(fmaxf(rmax[0], rmax[1]), fmaxf(rmax[2], rmax[3]));

    float sum = 0.f;
#pragma unroll
    for (int i = 0; i < 4; ++i) {
        v[i] = expf(v[i] - mx);
        sum += v[i];
    }
#pragma unroll
    for (int o = 1; o < 64; o <<= 1) sum += __shfl_xor(sum, o);
    if (lane == 0) rsum[wid] = sum;
    __syncthreads();
    sum = rsum[0] + rsum[1] + rsum[2] + rsum[3];

    const float inv = 1.0f / sum;
#pragma unroll
    for (int i = 0; i < 4; ++i) p[tid + 256 * i] = v[i] * inv;
}

// ---------------------------------------------------------------------------
// out[row] = LayerNorm(a[row] + r[row]) * w + b.  One block per row (D_=768).
// Safe when out == a or out == r (row fully read into regs before writes).
// ---------------------------------------------------------------------------
__global__ __launch_bounds__(256) void ln_residual(
    const float* __restrict__ a, const float* __restrict__ r,
    const float* __restrict__ w, const float* __restrict__ bb,
    float* __restrict__ out)
{
    const long row = blockIdx.x;
    const float* pa = a + row * (long)D_;
    const float* pr = r + row * (long)D_;
    const int tid  = threadIdx.x;
    const int lane = tid & 63, wid = tid >> 6;

    float v[3];
    float sum = 0.f;
#pragma unroll
    for (int i = 0; i < 3; ++i) {
        v[i] = pa[tid + 256 * i] + pr[tid + 256 * i];
        sum += v[i];
    }
#pragma unroll
    for (int o = 1; o < 64; o <<= 1) sum += __shfl_xor(sum, o);
    __shared__ float rs[4], rs2[4];
    if (lane == 0) rs[wid] = sum;
    __syncthreads();
    sum = rs[0] + rs[1] + rs[2] + rs[3];
    const float mu = sum * (1.0f / D_);

    float s2 = 0.f;
#pragma unroll
    for (int i = 0; i < 3; ++i) {
        float d = v[i] - mu;
        s2 += d * d;
    }
#pragma unroll
    for (int o = 1; o < 64; o <<= 1) s2 += __shfl_xor(s2, o);
    if (lane == 0) rs2[wid] = s2;
    __syncthreads();
    s2 = rs2[0] + rs2[1] + rs2[2] + rs2[3];

    const float rstd = rsqrtf(s2 * (1.0f / D_) + 1e-5f);
#pragma unroll
    for (int i = 0; i < 3; ++i) {
        const int c = tid + 256 * i;
        out[row * (long)D_ + c] = (v[i] - mu) * rstd * w[c] + bb[c];
    }
}

// ---------------------------------------------------------------------------
extern "C" void kernel_launch(void* const* d_in, const int* in_sizes, int n_in,
                              void* d_out, int out_size, void* d_ws, size_t ws_size,
                              hipStream_t stream)
{
    const float* src  = (const float*)d_in[0];
    const float* gu   = (const float*)d_in[1];
    const float* wq   = (const float*)d_in[2];
    const float* bq   = (const float*)d_in[3];
    const float* wk   = (const float*)d_in[4];
    const float* bk   = (const float*)d_in[5];
    const float* wv   = (const float*)d_in[6];
    const float* bv   = (const float*)d_in[7];
    const float* w1   = (const float*)d_in[8];
    const float* b1   = (const float*)d_in[9];
    const float* w2   = (const float*)d_in[10];
    const float* b2   = (const float*)d_in[11];
    const float* ln1w = (const float*)d_in[12];
    const float* ln1b = (const float*)d_in[13];
    const float* ln2w = (const float*)d_in[14];
    const float* ln2b = (const float*)d_in[15];
    float* out = (float*)d_out;

    // ---- Workspace layout (floats), peak = 3*ND + 4*S*S = 41.94M = 167.8 MB
    //   [0,ND)       q  -> attn_out (in-place PV) -> x (in-place LN1)
    //   [ND,2ND)     k  -> ffh chunk (4096 x 3072 = ND exactly)
    //   [2ND,3ND)    v  -> f2 (full ND)
    //   [3ND,+4SS)   scores for one 4-batch group
    const long ND = (long)NTOK * D_;       // 12,582,912
    const long SS = (long)S_ * S_;         // 1,048,576
    const size_t NEED = (size_t)(3 * ND + 4 * SS) * sizeof(float);  // 167,772,160
    if (ws_size < NEED) return;  // diagnostic gate: fail cleanly, don't fault

    float* ws   = (float*)d_ws;
    float* q    = ws;             // also attn_out, x
    float* k    = ws + ND;        // also ffh chunk
    float* v    = ws + 2 * ND;    // also f2
    float* scg  = ws + 3 * ND;    // group scores [4,S,S]
    float* ffh  = k;
    float* f2   = v;

    const dim3 blk(256);
    const float scale = 1.0f / sqrtf((float)D_);

    // q,k,v = src @ W + b                        [16384,768]x[768,768]
    gemm_f32<0, false><<<dim3(D_ / TN, NTOK / TM, 1), blk, 0, stream>>>(
        src, wq, bq, nullptr, q, NTOK, D_, D_, 0, 0, 0, 1.f);
    gemm_f32<0, false><<<dim3(D_ / TN, NTOK / TM, 1), blk, 0, stream>>>(
        src, wk, bk, nullptr, k, NTOK, D_, D_, 0, 0, 0, 1.f);
    gemm_f32<0, false><<<dim3(D_ / TN, NTOK / TM, 1), blk, 0, stream>>>(
        src, wv, bv, nullptr, v, NTOK, D_, D_, 0, 0, 0, 1.f);

    // ---- attention in 4-batch groups (scores buffer = 4*S*S) ----
    for (int g = 0; g < 4; ++g) {
        const long off = (long)g * 4 * S_ * D_;   // token offset (elements)
        // scores = q @ k^T * scale + gumbel(u)   batched [1024,768]x[768,1024]
        gemm_f32<2, true><<<dim3(S_ / TN, S_ / TM, 4), blk, 0, stream>>>(
            q + off, k + off, nullptr, gu + (long)g * 4 * SS, scg, S_, S_, D_,
            (long)S_ * D_, (long)S_ * D_, SS, scale);
        // softmax rows of the group
        softmax_rows<<<dim3(4 * S_), blk, 0, stream>>>(scg);
        // attn_out = attn @ v  -> in-place into q  batched [1024,1024]x[1024,768]
        gemm_f32<0, false><<<dim3(D_ / TN, S_ / TM, 4), blk, 0, stream>>>(
            scg, v + off, nullptr, nullptr, q + off, S_, D_, S_,
            SS, (long)S_ * D_, (long)S_ * D_, 1.f);
    }

    // x = LN(src + attn_out), in-place into q slot
    ln_residual<<<dim3(NTOK), blk, 0, stream>>>(src, q, ln1w, ln1b, q);

    // ---- feed-forward in 4 row-chunks of 4096 (ffh chunk fits in k slot) ----
    for (int c = 0; c < 4; ++c) {
        const long roff = (long)c * 4096;
        // ffh = gelu(x_chunk @ w1 + b1)           [4096,768]x[768,3072]
        gemm_f32<1, false><<<dim3(DFF_ / TN, 4096 / TM, 1), blk, 0, stream>>>(
            q + roff * D_, w1, b1, nullptr, ffh, 4096, DFF_, D_, 0, 0, 0, 1.f);
        // f2_chunk = ffh @ w2 + b2                [4096,3072]x[3072,768]
        gemm_f32<0, false><<<dim3(D_ / TN, 4096 / TM, 1), blk, 0, stream>>>(
            ffh, w2, b2, nullptr, f2 + roff * D_, 4096, D_, DFF_, 0, 0, 0, 1.f);
    }

    // out = LN(x + f2)
    ln_residual<<<dim3(NTOK), blk, 0, stream>>>(q, f2, ln2w, ln2b, out);
}

// Round 4
// 1313.531 us; speedup vs baseline: 3.0807x; 3.0807x over previous
//
#include <hip/hip_runtime.h>
#include <math.h>

#define B_   16
#define S_   1024
#define D_   768
#define DFF_ 3072
#define NTOK (B_ * S_)

typedef __attribute__((ext_vector_type(8))) short bfx8;
typedef __attribute__((ext_vector_type(4))) float fx4;

__device__ __forceinline__ short bf16_rne(float f) {
    union { float f; unsigned u; } x; x.f = f;
    return (short)((x.u + 0x7FFF + ((x.u >> 16) & 1)) >> 16);
}
__device__ __forceinline__ float bf16_to_f(unsigned short h) {
    union { unsigned u; float f; } x; x.u = ((unsigned)h) << 16;
    return x.f;
}

// ---------------------------------------------------------------------------
// MFMA bf16 GEMM: C[M,N] = A[M,K] @ Bt[N,K]^T (+ epilogue)
// 128x128 tile, BK=32, 256 threads = 4 waves in 2x2, each wave 64x64 (4x4
// frags of 16x16x32). A: fp32 (convert on stage) if AF32, else bf16.
// EPI 0: +bias(optional)   1: gelu(acc+bias)   2: acc*scale + gumbel(U)
// CST 0: f32 row-major     1: bf16 row-major   2: bf16 scattered as
//        vT[b*D + col][s]  (b=row/1024, s=row%1024) for the V operand of PV.
// Batched via blockIdx.z strides (elements).
// ---------------------------------------------------------------------------
template <int EPI, bool AF32, int CST>
__global__ __launch_bounds__(256) void gemm_mfma(
    const void* __restrict__ Av, const short* __restrict__ Bt,
    const float* __restrict__ bias, const float* __restrict__ U,
    void* __restrict__ Cv, int M, int N, int K,
    long bsA, long bsB, long bsC, float scale)
{
    const int bz   = blockIdx.z;
    const int tid  = threadIdx.x;
    const int brow = blockIdx.y * 128;
    const int bcol = blockIdx.x * 128;
    const int lane = tid & 63;
    const int wave = tid >> 6;
    const int wm   = wave >> 1, wn = wave & 1;

    __shared__ short As[128][40];  // row stride 80 B: rows r,r+8 alias = 2-way (free)
    __shared__ short Bs[128][40];

    fx4 acc[4][4];
#pragma unroll
    for (int i = 0; i < 4; ++i)
#pragma unroll
        for (int j = 0; j < 4; ++j)
#pragma unroll
            for (int e = 0; e < 4; ++e) acc[i][j][e] = 0.f;

    const float* Af  = (const float*)Av + (long)bz * bsA;
    const short* Ah  = (const short*)Av + (long)bz * bsA;
    const short* Btb = Bt + (long)bz * bsB;

    const int sr = tid >> 1;          // 0..127 staging row
    const int sk = (tid & 1) * 16;    // 0 / 16

    for (int k0 = 0; k0 < K; k0 += 32) {
        if (AF32) {
            const float* ap = Af + (long)(brow + sr) * K + k0 + sk;
            float4 f0 = *(const float4*)(ap);
            float4 f1 = *(const float4*)(ap + 4);
            float4 f2 = *(const float4*)(ap + 8);
            float4 f3 = *(const float4*)(ap + 12);
            bfx8 h0, h1;
            h0[0]=bf16_rne(f0.x); h0[1]=bf16_rne(f0.y); h0[2]=bf16_rne(f0.z); h0[3]=bf16_rne(f0.w);
            h0[4]=bf16_rne(f1.x); h0[5]=bf16_rne(f1.y); h0[6]=bf16_rne(f1.z); h0[7]=bf16_rne(f1.w);
            h1[0]=bf16_rne(f2.x); h1[1]=bf16_rne(f2.y); h1[2]=bf16_rne(f2.z); h1[3]=bf16_rne(f2.w);
            h1[4]=bf16_rne(f3.x); h1[5]=bf16_rne(f3.y); h1[6]=bf16_rne(f3.z); h1[7]=bf16_rne(f3.w);
            *(bfx8*)&As[sr][sk]     = h0;
            *(bfx8*)&As[sr][sk + 8] = h1;
        } else {
            const short* ap = Ah + (long)(brow + sr) * K + k0 + sk;
            *(bfx8*)&As[sr][sk]     = *(const bfx8*)(ap);
            *(bfx8*)&As[sr][sk + 8] = *(const bfx8*)(ap + 8);
        }
        {
            const short* bp = Btb + (long)(bcol + sr) * K + k0 + sk;
            *(bfx8*)&Bs[sr][sk]     = *(const bfx8*)(bp);
            *(bfx8*)&Bs[sr][sk + 8] = *(const bfx8*)(bp + 8);
        }
        __syncthreads();

        const int kg = (lane >> 4) * 8;
        bfx8 a[4], b[4];
#pragma unroll
        for (int i = 0; i < 4; ++i) {
            a[i] = *(const bfx8*)&As[wm * 64 + i * 16 + (lane & 15)][kg];
            b[i] = *(const bfx8*)&Bs[wn * 64 + i * 16 + (lane & 15)][kg];
        }
#pragma unroll
        for (int mi = 0; mi < 4; ++mi)
#pragma unroll
            for (int ni = 0; ni < 4; ++ni)
                acc[mi][ni] = __builtin_amdgcn_mfma_f32_16x16x32_bf16(
                    a[mi], b[ni], acc[mi][ni], 0, 0, 0);
        __syncthreads();
    }

    // Epilogue. C/D layout (m89-verified): col = lane&15, row = (lane>>4)*4+e.
    const int r0 = brow + wm * 64;
    const int c0 = bcol + wn * 64;
#pragma unroll
    for (int mi = 0; mi < 4; ++mi) {
#pragma unroll
        for (int ni = 0; ni < 4; ++ni) {
            const int col = c0 + ni * 16 + (lane & 15);
#pragma unroll
            for (int e = 0; e < 4; ++e) {
                const int row = r0 + mi * 16 + (lane >> 4) * 4 + e;
                float val = acc[mi][ni][e];
                if (EPI == 0) {
                    if (bias) val += bias[col];
                } else if (EPI == 1) {
                    val += bias[col];
                    val = 0.5f * val * (1.0f + erff(val * 0.70710678118654752f));
                } else if (EPI == 2) {
                    float u = U[(long)bz * bsC + (long)row * N + col];
                    val = val * scale - logf(-logf(u));
                }
                if (CST == 0) {
                    ((float*)Cv)[(long)bz * bsC + (long)row * N + col] = val;
                } else if (CST == 1) {
                    ((short*)Cv)[(long)bz * bsC + (long)row * N + col] = bf16_rne(val);
                } else {
                    const int bb = row >> 10, s = row & 1023;
                    ((short*)Cv)[((long)(bb * D_) + col) * S_ + s] = bf16_rne(val);
                }
            }
        }
    }
}

// ---------------------------------------------------------------------------
// W [K,N] fp32 -> WT [N,K] bf16.  block (256) = 32x8, 32x32 tiles.
// ---------------------------------------------------------------------------
__global__ __launch_bounds__(256) void transpose_cast_w(
    const float* __restrict__ W, short* __restrict__ WT, int K, int N)
{
    __shared__ float t[32][33];
    const int n0 = blockIdx.x * 32, k0 = blockIdx.y * 32;
    const int tx = threadIdx.x & 31, ty = threadIdx.x >> 5;
#pragma unroll
    for (int i = 0; i < 4; ++i)
        t[ty * 4 + i][tx] = W[(long)(k0 + ty * 4 + i) * N + n0 + tx];
    __syncthreads();
#pragma unroll
    for (int i = 0; i < 4; ++i)
        WT[(long)(n0 + ty * 4 + i) * K + k0 + tx] = bf16_rne(t[tx][ty * 4 + i]);
}

// ---------------------------------------------------------------------------
// Row softmax: f32 in, bf16 out. One 256-thread block per row (1024).
// ---------------------------------------------------------------------------
__global__ __launch_bounds__(256) void softmax_rows(
    const float* __restrict__ sc, short* __restrict__ P)
{
    const long row = blockIdx.x;
    const float* p = sc + row * (long)S_;
    const int tid = threadIdx.x, lane = tid & 63, wid = tid >> 6;

    float v[4];
    float mx = -INFINITY;
#pragma unroll
    for (int i = 0; i < 4; ++i) { v[i] = p[tid + 256 * i]; mx = fmaxf(mx, v[i]); }
#pragma unroll
    for (int o = 1; o < 64; o <<= 1) mx = fmaxf(mx, __shfl_xor(mx, o));
    __shared__ float rmax[4], rsum[4];
    if (lane == 0) rmax[wid] = mx;
    __syncthreads();
    mx = fmaxf(fmaxf(rmax[0], rmax[1]), fmaxf(rmax[2], rmax[3]));

    float sum = 0.f;
#pragma unroll
    for (int i = 0; i < 4; ++i) { v[i] = expf(v[i] - mx); sum += v[i]; }
#pragma unroll
    for (int o = 1; o < 64; o <<= 1) sum += __shfl_xor(sum, o);
    if (lane == 0) rsum[wid] = sum;
    __syncthreads();
    sum = rsum[0] + rsum[1] + rsum[2] + rsum[3];

    const float inv = 1.0f / sum;
#pragma unroll
    for (int i = 0; i < 4; ++i)
        P[row * (long)S_ + tid + 256 * i] = bf16_rne(v[i] * inv);
}

// ---------------------------------------------------------------------------
// out = LN(a + r) * w + b.  a fp32; r bf16 if RBF else fp32. Row = blockIdx.
// ---------------------------------------------------------------------------
template <bool RBF>
__global__ __launch_bounds__(256) void ln_residual(
    const float* __restrict__ a, const void* __restrict__ rv,
    const float* __restrict__ w, const float* __restrict__ bb,
    float* __restrict__ out)
{
    const long row = blockIdx.x;
    const float* pa = a + row * (long)D_;
    const int tid = threadIdx.x, lane = tid & 63, wid = tid >> 6;

    float v[3];
    float sum = 0.f;
#pragma unroll
    for (int i = 0; i < 3; ++i) {
        const int c = tid + 256 * i;
        float rvv = RBF ? bf16_to_f(((const unsigned short*)rv)[row * (long)D_ + c])
                        : ((const float*)rv)[row * (long)D_ + c];
        v[i] = pa[c] + rvv;
        sum += v[i];
    }
#pragma unroll
    for (int o = 1; o < 64; o <<= 1) sum += __shfl_xor(sum, o);
    __shared__ float rs[4], rs2[4];
    if (lane == 0) rs[wid] = sum;
    __syncthreads();
    sum = rs[0] + rs[1] + rs[2] + rs[3];
    const float mu = sum * (1.0f / D_);

    float s2 = 0.f;
#pragma unroll
    for (int i = 0; i < 3; ++i) { float d = v[i] - mu; s2 += d * d; }
#pragma unroll
    for (int o = 1; o < 64; o <<= 1) s2 += __shfl_xor(s2, o);
    if (lane == 0) rs2[wid] = s2;
    __syncthreads();
    s2 = rs2[0] + rs2[1] + rs2[2] + rs2[3];

    const float rstd = rsqrtf(s2 * (1.0f / D_) + 1e-5f);
#pragma unroll
    for (int i = 0; i < 3; ++i) {
        const int c = tid + 256 * i;
        out[row * (long)D_ + c] = (v[i] - mu) * rstd * w[c] + bb[c];
    }
}

// ---------------------------------------------------------------------------
extern "C" void kernel_launch(void* const* d_in, const int* in_sizes, int n_in,
                              void* d_out, int out_size, void* d_ws, size_t ws_size,
                              hipStream_t stream)
{
    const float* src  = (const float*)d_in[0];
    const float* gu   = (const float*)d_in[1];
    const float* wq   = (const float*)d_in[2];
    const float* bq   = (const float*)d_in[3];
    const float* wk   = (const float*)d_in[4];
    const float* bk   = (const float*)d_in[5];
    const float* wv   = (const float*)d_in[6];
    const float* bv   = (const float*)d_in[7];
    const float* w1   = (const float*)d_in[8];
    const float* b1   = (const float*)d_in[9];
    const float* w2   = (const float*)d_in[10];
    const float* b2   = (const float*)d_in[11];
    const float* ln1w = (const float*)d_in[12];
    const float* ln1b = (const float*)d_in[13];
    const float* ln2w = (const float*)d_in[14];
    const float* ln2b = (const float*)d_in[15];
    float* out = (float*)d_out;

    // ---- Workspace (bytes), peak 164.0 MB <= 167.8 MB proven available ----
    const long ND = (long)NTOK * D_;   // 12,582,912 elems
    const long SS = (long)S_ * S_;     // 1,048,576 elems
    char* base = (char*)d_ws;
    short* q_bf   = (short*)(base);                    // ND bf16; -> attn (in-place) -> ffh chunk
    short* k_bf   = (short*)(base + 25165824);         // ND bf16; -> f2 chunk (f32) later
    short* vT_bf  = (short*)(base + 50331648);         // ND bf16 as [B][D][S]
    float* scg    = (float*)(base + 75497472);         // 4*SS f32 scores group
    short* P_bf   = (short*)(base + 92274688);         // 4*SS bf16
    float* x_f32  = (float*)(base + 100663296);        // ND f32
    short* wqT    = (short*)(base + 150994944);        // 768*768 bf16
    short* wkT    = wqT + 589824;
    short* wvT    = wkT + 589824;
    short* w1T    = wvT + 589824;                      // [3072,768]
    short* w2T    = w1T + (long)D_ * DFF_;             // [768,3072]
    const size_t NEED = 163971072;
    if (ws_size < NEED) return;  // fail cleanly, don't fault

    short* ffh = q_bf;            // [4096,3072] bf16 chunk (q dead by FF)
    float* f2  = (float*)k_bf;    // [4096,768] f32 chunk  (k dead by FF)

    const dim3 blk(256);
    const float scale = 1.0f / sqrtf((float)D_);

    // ---- weights -> bf16 transposed ----
    transpose_cast_w<<<dim3(D_ / 32, D_ / 32), blk, 0, stream>>>(wq, wqT, D_, D_);
    transpose_cast_w<<<dim3(D_ / 32, D_ / 32), blk, 0, stream>>>(wk, wkT, D_, D_);
    transpose_cast_w<<<dim3(D_ / 32, D_ / 32), blk, 0, stream>>>(wv, wvT, D_, D_);
    transpose_cast_w<<<dim3(DFF_ / 32, D_ / 32), blk, 0, stream>>>(w1, w1T, D_, DFF_);
    transpose_cast_w<<<dim3(D_ / 32, DFF_ / 32), blk, 0, stream>>>(w2, w2T, DFF_, D_);

    // ---- QKV: [16384,768] x [768,768], A = src fp32 ----
    gemm_mfma<0, true, 1><<<dim3(D_ / 128, NTOK / 128, 1), blk, 0, stream>>>(
        src, wqT, bq, nullptr, q_bf, NTOK, D_, D_, 0, 0, 0, 1.f);
    gemm_mfma<0, true, 1><<<dim3(D_ / 128, NTOK / 128, 1), blk, 0, stream>>>(
        src, wkT, bk, nullptr, k_bf, NTOK, D_, D_, 0, 0, 0, 1.f);
    gemm_mfma<0, true, 2><<<dim3(D_ / 128, NTOK / 128, 1), blk, 0, stream>>>(
        src, wvT, bv, nullptr, vT_bf, NTOK, D_, D_, 0, 0, 0, 1.f);

    // ---- attention in 4-batch groups ----
    for (int g = 0; g < 4; ++g) {
        const long toff = (long)g * 4 * S_ * D_;  // token-element offset
        // scores = q @ k^T * scale + gumbel
        gemm_mfma<2, false, 0><<<dim3(S_ / 128, S_ / 128, 4), blk, 0, stream>>>(
            q_bf + toff, k_bf + toff, nullptr, gu + (long)g * 4 * SS, scg,
            S_, S_, D_, (long)S_ * D_, (long)S_ * D_, SS, scale);
        // P = softmax(scores) -> bf16
        softmax_rows<<<dim3(4 * S_), blk, 0, stream>>>(scg, P_bf);
        // attn = P @ V  (B^T = vT[b]) -> bf16, in-place into q slot
        gemm_mfma<0, false, 1><<<dim3(D_ / 128, S_ / 128, 4), blk, 0, stream>>>(
            P_bf, vT_bf + (long)g * 4 * D_ * S_, nullptr, nullptr, q_bf + toff,
            S_, D_, S_, SS, (long)D_ * S_, (long)S_ * D_, 1.f);
    }

    // ---- x = LN(src + attn) ----
    ln_residual<true><<<dim3(NTOK), blk, 0, stream>>>(src, q_bf, ln1w, ln1b, x_f32);

    // ---- FF in 4 row-chunks of 4096 ----
    for (int c = 0; c < 4; ++c) {
        const long roff = (long)c * 4096;
        gemm_mfma<1, true, 1><<<dim3(DFF_ / 128, 4096 / 128, 1), blk, 0, stream>>>(
            x_f32 + roff * D_, w1T, b1, nullptr, ffh, 4096, DFF_, D_, 0, 0, 0, 1.f);
        gemm_mfma<0, false, 0><<<dim3(D_ / 128, 4096 / 128, 1), blk, 0, stream>>>(
            ffh, w2T, b2, nullptr, f2, 4096, D_, DFF_, 0, 0, 0, 1.f);
        ln_residual<false><<<dim3(4096), blk, 0, stream>>>(
            x_f32 + roff * D_, f2, ln2w, ln2b, out + roff * D_);
    }
}

// Round 8
// 898.559 us; speedup vs baseline: 4.5034x; 1.4618x over previous
//
#include <hip/hip_runtime.h>
#include <math.h>

#define B_   16
#define S_   1024
#define D_   768
#define DFF_ 3072
#define NTOK (B_ * S_)

typedef __attribute__((ext_vector_type(8))) short bfx8;
typedef __attribute__((ext_vector_type(4))) float fx4;

__device__ __forceinline__ short bf16_rne(float f) {
    union { float f; unsigned u; } x; x.f = f;
    return (short)((x.u + 0x7FFF + ((x.u >> 16) & 1)) >> 16);
}
__device__ __forceinline__ float bf16_to_f(unsigned short h) {
    union { unsigned u; float f; } x; x.u = ((unsigned)h) << 16;
    return x.f;
}

// ---------------------------------------------------------------------------
// MFMA bf16 GEMM: C[M,N] = A[M,K](bf16) @ Bt[N,K](bf16)^T (+ epilogue)
// 128x128 tile, BK=32, 256 threads = 4 waves (2x2), wave = 64x64 = 4x4 frags
// of 16x16x32. EPI 0:+bias(opt) 1:gelu(acc+bias) 2:acc*scale+gumbel(U)
// CST 0: f32 row-major  1: bf16 row-major  2: bf16 scattered vT[b*D+col][s]
// Batched via blockIdx.z element strides.
// ---------------------------------------------------------------------------
template <int EPI, int CST>
__global__ __launch_bounds__(256) void gemm_mfma(
    const short* __restrict__ A, const short* __restrict__ Bt,
    const float* __restrict__ bias, const float* __restrict__ U,
    void* __restrict__ Cv, int M, int N, int K,
    long bsA, long bsB, long bsC, float scale)
{
    const int bz   = blockIdx.z;
    const int tid  = threadIdx.x;
    const int brow = blockIdx.y * 128;
    const int bcol = blockIdx.x * 128;
    const int lane = tid & 63;
    const int wave = tid >> 6;
    const int wm   = wave >> 1, wn = wave & 1;

    __shared__ short As[128][40];  // 80B row pitch: reads ~2-way (free, m136)
    __shared__ short Bs[128][40];

    fx4 acc[4][4];
#pragma unroll
    for (int i = 0; i < 4; ++i)
#pragma unroll
        for (int j = 0; j < 4; ++j)
#pragma unroll
            for (int e = 0; e < 4; ++e) acc[i][j][e] = 0.f;

    const short* Ab  = A + (long)bz * bsA;
    const short* Btb = Bt + (long)bz * bsB;

    const int sr = tid >> 1;          // staging row 0..127
    const int sk = (tid & 1) * 16;    // short offset 0/16

    for (int k0 = 0; k0 < K; k0 += 32) {
        {
            const short* ap = Ab + (long)(brow + sr) * K + k0 + sk;
            *(bfx8*)&As[sr][sk]     = *(const bfx8*)(ap);
            *(bfx8*)&As[sr][sk + 8] = *(const bfx8*)(ap + 8);
            const short* bp = Btb + (long)(bcol + sr) * K + k0 + sk;
            *(bfx8*)&Bs[sr][sk]     = *(const bfx8*)(bp);
            *(bfx8*)&Bs[sr][sk + 8] = *(const bfx8*)(bp + 8);
        }
        __syncthreads();

        const int kg = (lane >> 4) * 8;
        bfx8 a[4], b[4];
#pragma unroll
        for (int i = 0; i < 4; ++i) {
            a[i] = *(const bfx8*)&As[wm * 64 + i * 16 + (lane & 15)][kg];
            b[i] = *(const bfx8*)&Bs[wn * 64 + i * 16 + (lane & 15)][kg];
        }
#pragma unroll
        for (int mi = 0; mi < 4; ++mi)
#pragma unroll
            for (int ni = 0; ni < 4; ++ni)
                acc[mi][ni] = __builtin_amdgcn_mfma_f32_16x16x32_bf16(
                    a[mi], b[ni], acc[mi][ni], 0, 0, 0);
        __syncthreads();
    }

    // Epilogue. C/D layout (m89): col = lane&15, row = (lane>>4)*4 + e.
    const int r0 = brow + wm * 64;
    const int c0 = bcol + wn * 64;
#pragma unroll
    for (int mi = 0; mi < 4; ++mi) {
#pragma unroll
        for (int ni = 0; ni < 4; ++ni) {
            const int col = c0 + ni * 16 + (lane & 15);
#pragma unroll
            for (int e = 0; e < 4; ++e) {
                const int row = r0 + mi * 16 + (lane >> 4) * 4 + e;
                float val = acc[mi][ni][e];
                if (EPI == 0) {
                    if (bias) val += bias[col];
                } else if (EPI == 1) {
                    val += bias[col];
                    val = 0.5f * val * (1.0f + erff(val * 0.70710678118654752f));
                } else if (EPI == 2) {
                    float u = U[(long)bz * bsC + (long)row * N + col];
                    val = val * scale - logf(-logf(u));
                }
                if (CST == 0) {
                    ((float*)Cv)[(long)bz * bsC + (long)row * N + col] = val;
                } else if (CST == 1) {
                    ((short*)Cv)[(long)bz * bsC + (long)row * N + col] = bf16_rne(val);
                } else {
                    const int bb = row >> 10, s = row & 1023;
                    ((short*)Cv)[((long)(bb * D_) + col) * S_ + s] = bf16_rne(val);
                }
            }
        }
    }
}

// ---------------------------------------------------------------------------
// W [K,N] fp32 -> WT [N,K] bf16.
// ---------------------------------------------------------------------------
__global__ __launch_bounds__(256) void transpose_cast_w(
    const float* __restrict__ W, short* __restrict__ WT, int K, int N)
{
    __shared__ float t[32][33];
    const int n0 = blockIdx.x * 32, k0 = blockIdx.y * 32;
    const int tx = threadIdx.x & 31, ty = threadIdx.x >> 5;
#pragma unroll
    for (int i = 0; i < 4; ++i)
        t[ty * 4 + i][tx] = W[(long)(k0 + ty * 4 + i) * N + n0 + tx];
    __syncthreads();
#pragma unroll
    for (int i = 0; i < 4; ++i)
        WT[(long)(n0 + ty * 4 + i) * K + k0 + tx] = bf16_rne(t[tx][ty * 4 + i]);
}

// ---------------------------------------------------------------------------
// f32 -> bf16 elementwise, 8/thread (n must be multiple of 8*256).
// ---------------------------------------------------------------------------
__global__ __launch_bounds__(256) void cast_bf(
    const float* __restrict__ in, short* __restrict__ o)
{
    const long i = ((long)blockIdx.x * 256 + threadIdx.x) * 8;
    float4 f0 = *(const float4*)(in + i);
    float4 f1 = *(const float4*)(in + i + 4);
    bfx8 h;
    h[0]=bf16_rne(f0.x); h[1]=bf16_rne(f0.y); h[2]=bf16_rne(f0.z); h[3]=bf16_rne(f0.w);
    h[4]=bf16_rne(f1.x); h[5]=bf16_rne(f1.y); h[6]=bf16_rne(f1.z); h[7]=bf16_rne(f1.w);
    *(bfx8*)(o + i) = h;
}

// ---------------------------------------------------------------------------
// Row softmax: f32 in, bf16 out. One block per row (1024).
// ---------------------------------------------------------------------------
__global__ __launch_bounds__(256) void softmax_rows(
    const float* __restrict__ sc, short* __restrict__ P)
{
    const long row = blockIdx.x;
    const float* p = sc + row * (long)S_;
    const int tid = threadIdx.x, lane = tid & 63, wid = tid >> 6;

    float v[4];
    float mx = -INFINITY;
#pragma unroll
    for (int i = 0; i < 4; ++i) { v[i] = p[tid + 256 * i]; mx = fmaxf(mx, v[i]); }
#pragma unroll
    for (int o = 1; o < 64; o <<= 1) mx = fmaxf(mx, __shfl_xor(mx, o));
    __shared__ float rmax[4], rsum[4];
    if (lane == 0) rmax[wid] = mx;
    __syncthreads();
    mx = fmaxf(fmaxf(rmax[0], rmax[1]), fmaxf(rmax[2], rmax[3]));

    float sum = 0.f;
#pragma unroll
    for (int i = 0; i < 4; ++i) { v[i] = expf(v[i] - mx); sum += v[i]; }
#pragma unroll
    for (int o = 1; o < 64; o <<= 1) sum += __shfl_xor(sum, o);
    if (lane == 0) rsum[wid] = sum;
    __syncthreads();
    sum = rsum[0] + rsum[1] + rsum[2] + rsum[3];

    const float inv = 1.0f / sum;
#pragma unroll
    for (int i = 0; i < 4; ++i)
        P[row * (long)S_ + tid + 256 * i] = bf16_rne(v[i] * inv);
}

// ---------------------------------------------------------------------------
// out = LN(a + r) * w + b.  a f32; r bf16 if RBF else f32.
// WBF: additionally write bf16 copy of LN output to obf.
// Safe in-place (out==r as f32): row fully read before writes.
// ---------------------------------------------------------------------------
template <bool RBF, bool WBF>
__global__ __launch_bounds__(256) void ln_residual(
    const float* __restrict__ a, const void* __restrict__ rv,
    const float* __restrict__ w, const float* __restrict__ bb,
    float* __restrict__ out, short* __restrict__ obf)
{
    const long row = blockIdx.x;
    const float* pa = a + row * (long)D_;
    const int tid = threadIdx.x, lane = tid & 63, wid = tid >> 6;

    float v[3];
    float sum = 0.f;
#pragma unroll
    for (int i = 0; i < 3; ++i) {
        const int c = tid + 256 * i;
        float rvv = RBF ? bf16_to_f(((const unsigned short*)rv)[row * (long)D_ + c])
                        : ((const float*)rv)[row * (long)D_ + c];
        v[i] = pa[c] + rvv;
        sum += v[i];
    }
#pragma unroll
    for (int o = 1; o < 64; o <<= 1) sum += __shfl_xor(sum, o);
    __shared__ float rs[4], rs2[4];
    if (lane == 0) rs[wid] = sum;
    __syncthreads();
    sum = rs[0] + rs[1] + rs[2] + rs[3];
    const float mu = sum * (1.0f / D_);

    float s2 = 0.f;
#pragma unroll
    for (int i = 0; i < 3; ++i) { float d = v[i] - mu; s2 += d * d; }
#pragma unroll
    for (int o = 1; o < 64; o <<= 1) s2 += __shfl_xor(s2, o);
    if (lane == 0) rs2[wid] = s2;
    __syncthreads();
    s2 = rs2[0] + rs2[1] + rs2[2] + rs2[3];

    const float rstd = rsqrtf(s2 * (1.0f / D_) + 1e-5f);
#pragma unroll
    for (int i = 0; i < 3; ++i) {
        const int c = tid + 256 * i;
        const float y = (v[i] - mu) * rstd * w[c] + bb[c];
        out[row * (long)D_ + c] = y;
        if (WBF) obf[row * (long)D_ + c] = bf16_rne(y);
    }
}

// ---------------------------------------------------------------------------
extern "C" void kernel_launch(void* const* d_in, const int* in_sizes, int n_in,
                              void* d_out, int out_size, void* d_ws, size_t ws_size,
                              hipStream_t stream)
{
    const float* src  = (const float*)d_in[0];
    const float* gu   = (const float*)d_in[1];
    const float* wq   = (const float*)d_in[2];
    const float* bq   = (const float*)d_in[3];
    const float* wk   = (const float*)d_in[4];
    const float* bk   = (const float*)d_in[5];
    const float* wv   = (const float*)d_in[6];
    const float* bv   = (const float*)d_in[7];
    const float* w1   = (const float*)d_in[8];
    const float* b1   = (const float*)d_in[9];
    const float* w2   = (const float*)d_in[10];
    const float* b2   = (const float*)d_in[11];
    const float* ln1w = (const float*)d_in[12];
    const float* ln1b = (const float*)d_in[13];
    const float* ln2w = (const float*)d_in[14];
    const float* ln2b = (const float*)d_in[15];
    float* out = (float*)d_out;

    // ---- Workspace (bytes). Peak 163,971,072 == Round-4 NEED (proven). ----
    //  [0,        25165824)  q_bf   (attn in-place; ffh overlays at FF)
    //  [25165824, 50331648)  k_bf   (ffh tail)
    //  [50331648, 75497472)  vT_bf  [B][D][S]
    //  [75497472,109051904)  scg8 f32 (8*S*S)      } -> x_f32 after attention
    //  [109051904,125829120) P8_bf  (8*S*S bf16)   }    (exactly 50,331,648 B)
    //  [125829120,150994944) src_bf -> x_bf (src_bf dead after QKV)
    //  [150994944,163971072) wqT wkT wvT w1T w2T (bf16)
    char* base = (char*)d_ws;
    short* q_bf   = (short*)(base);
    short* k_bf   = (short*)(base + 25165824);
    short* vT_bf  = (short*)(base + 50331648);
    float* scg    = (float*)(base + 75497472);
    short* P_bf   = (short*)(base + 109051904);
    float* x_f32  = (float*)(base + 75497472);
    short* srcx_bf= (short*)(base + 125829120);   // src_bf, then x_bf
    short* wqT    = (short*)(base + 150994944);
    short* wkT    = wqT + 589824;
    short* wvT    = wkT + 589824;
    short* w1T    = wvT + 589824;
    short* w2T    = w1T + (long)D_ * DFF_;
    const size_t NEED = 163971072;
    if (ws_size < NEED) return;

    short* ffh = q_bf;   // [8192,3072] bf16 chunk = 50,331,648 B over q+k
    const long SS = (long)S_ * S_;

    const dim3 blk(256);
    const float scale = 1.0f / sqrtf((float)D_);

    // ---- prep: weights -> bf16^T; src -> bf16 ----
    transpose_cast_w<<<dim3(D_ / 32, D_ / 32), blk, 0, stream>>>(wq, wqT, D_, D_);
    transpose_cast_w<<<dim3(D_ / 32, D_ / 32), blk, 0, stream>>>(wk, wkT, D_, D_);
    transpose_cast_w<<<dim3(D_ / 32, D_ / 32), blk, 0, stream>>>(wv, wvT, D_, D_);
    transpose_cast_w<<<dim3(DFF_ / 32, D_ / 32), blk, 0, stream>>>(w1, w1T, D_, DFF_);
    transpose_cast_w<<<dim3(D_ / 32, DFF_ / 32), blk, 0, stream>>>(w2, w2T, DFF_, D_);
    cast_bf<<<dim3(6144), blk, 0, stream>>>(src, srcx_bf);

    // ---- QKV: [16384,768]x[768,768], grids 6x128 = 768 blocks ----
    gemm_mfma<0, 1><<<dim3(D_ / 128, NTOK / 128, 1), blk, 0, stream>>>(
        srcx_bf, wqT, bq, nullptr, q_bf, NTOK, D_, D_, 0, 0, 0, 1.f);
    gemm_mfma<0, 1><<<dim3(D_ / 128, NTOK / 128, 1), blk, 0, stream>>>(
        srcx_bf, wkT, bk, nullptr, k_bf, NTOK, D_, D_, 0, 0, 0, 1.f);
    gemm_mfma<0, 2><<<dim3(D_ / 128, NTOK / 128, 1), blk, 0, stream>>>(
        srcx_bf, wvT, bv, nullptr, vT_bf, NTOK, D_, D_, 0, 0, 0, 1.f);

    // ---- attention: 2 groups of 8 batches ----
    for (int g = 0; g < 2; ++g) {
        const long toff = (long)g * 8 * S_ * D_;
        // scores = q @ k^T * scale + gumbel   grid 8x8x8 = 512
        gemm_mfma<2, 0><<<dim3(S_ / 128, S_ / 128, 8), blk, 0, stream>>>(
            q_bf + toff, k_bf + toff, nullptr, gu + (long)g * 8 * SS, scg,
            S_, S_, D_, (long)S_ * D_, (long)S_ * D_, SS, scale);
        // P = softmax(scores) -> bf16
        softmax_rows<<<dim3(8 * S_), blk, 0, stream>>>(scg, P_bf);
        // attn = P @ V -> in-place into q slot   grid 6x8x8 = 384
        gemm_mfma<0, 1><<<dim3(D_ / 128, S_ / 128, 8), blk, 0, stream>>>(
            P_bf, vT_bf + (long)g * 8 * D_ * S_, nullptr, nullptr, q_bf + toff,
            S_, D_, S_, SS, (long)D_ * S_, (long)S_ * D_, 1.f);
    }

    // ---- x = LN(src + attn): write f32 (residual) + bf16 (FF1 input) ----
    ln_residual<true, true><<<dim3(NTOK), blk, 0, stream>>>(
        src, q_bf, ln1w, ln1b, x_f32, srcx_bf);

    // ---- FF: 2 chunks of 8192 rows ----
    for (int c = 0; c < 2; ++c) {
        const long roff = (long)c * 8192;
        // ffh = gelu(x @ w1 + b1)   grid 24x64 = 1536
        gemm_mfma<1, 1><<<dim3(DFF_ / 128, 8192 / 128, 1), blk, 0, stream>>>(
            srcx_bf + roff * D_, w1T, b1, nullptr, ffh, 8192, DFF_, D_, 0, 0, 0, 1.f);
        // f2 = ffh @ w2 + b2 -> out rows (f32)   grid 6x64 = 384
        gemm_mfma<0, 0><<<dim3(D_ / 128, 8192 / 128, 1), blk, 0, stream>>>(
            ffh, w2T, b2, nullptr, out + roff * D_, 8192, D_, DFF_, 0, 0, 0, 1.f);
        // out = LN(x + f2) in place
        ln_residual<false, false><<<dim3(8192), blk, 0, stream>>>(
            x_f32 + roff * D_, out + roff * D_, ln2w, ln2b, out + roff * D_, nullptr);
    }
}